// Round 1
// baseline (325.870 us; speedup 1.0000x reference)
//
#include <hip/hip_runtime.h>
#include <math.h>
#include <limits.h>

#define B_  8
#define L_  128
#define VF_ 32128
#define V_  32100
#define D_  768

// ---------------------------------------------------------------------------
// Kernel 1: per-(b,l) argmax over VF of logits+gumbel. One 256-thread block
// per row; float4 vector loads; first-index tie-break (jnp.argmax semantics).
// ---------------------------------------------------------------------------
__global__ __launch_bounds__(256) void k_argmax(
    const float* __restrict__ logits, const float* __restrict__ gumbel,
    int* __restrict__ amax)
{
    const int row = blockIdx.x;                       // 0..1023
    const float4* lp = (const float4*)(logits + (size_t)row * VF_);
    const float4* gp = (const float4*)(gumbel + (size_t)row * VF_);
    const int NV4 = VF_ / 4;                          // 8032

    float best = -INFINITY;
    int   bidx = 0;
    for (int i = threadIdx.x; i < NV4; i += 256) {
        float4 a = lp[i];
        float4 g = gp[i];
        float v;
        v = a.x + g.x; if (v > best) { best = v; bidx = 4*i + 0; }
        v = a.y + g.y; if (v > best) { best = v; bidx = 4*i + 1; }
        v = a.z + g.z; if (v > best) { best = v; bidx = 4*i + 2; }
        v = a.w + g.w; if (v > best) { best = v; bidx = 4*i + 3; }
    }
    // wave (64-lane) reduction, first-index tie-break
    for (int off = 32; off > 0; off >>= 1) {
        float ov = __shfl_down(best, off, 64);
        int   oi = __shfl_down(bidx, off, 64);
        if (ov > best || (ov == best && oi < bidx)) { best = ov; bidx = oi; }
    }
    __shared__ float s_v[4];
    __shared__ int   s_i[4];
    const int wave = threadIdx.x >> 6;
    if ((threadIdx.x & 63) == 0) { s_v[wave] = best; s_i[wave] = bidx; }
    __syncthreads();
    if (threadIdx.x == 0) {
        for (int w = 1; w < 4; ++w)
            if (s_v[w] > best || (s_v[w] == best && s_i[w] < bidx)) {
                best = s_v[w]; bidx = s_i[w];
            }
        amax[row] = bidx;
    }
}

// ---------------------------------------------------------------------------
// Kernel 2: per-batch control logic. One block per b, one thread per l.
// Reproduces: flipped/keep/extr, shifts, src=(l-len)%L, idx gather,
// flag = cumsum(idx!=0) > 0.  Emits up to two W-row indices per (b,l)
// (rowA = straight-through part, rowB = psg part; -1 = no contribution)
// and nn_idx (as float) directly into the output tail.
// ---------------------------------------------------------------------------
__global__ __launch_bounds__(128) void k_rowsel(
    const int* __restrict__ rwrt, const int* __restrict__ psg,
    const int* __restrict__ amax,
    int* __restrict__ rowA, int* __restrict__ rowB,
    float* __restrict__ nn_out)
{
    const int b = blockIdx.x;
    const int l = threadIdx.x;

    __shared__ int s_att[L_];
    __shared__ int s_extr[L_];
    __shared__ int s_len;
    __shared__ int s_first;

    const int att = rwrt[b * L_ + l];
    s_att[l] = att;
    if (l == 0) s_first = INT_MAX;
    __syncthreads();

    if (l == 0) {
        int len = 0;
        for (int i = 0; i < L_; ++i) len += (s_att[i] == 1);
        s_len = len;
    }
    // keep = 1 - fliplr(att);  extr = keep * psg
    const int keep = 1 - s_att[L_ - 1 - l];
    s_extr[l] = keep * psg[b * L_ + l];
    __syncthreads();

    const int len  = s_len;
    const int src  = (l - len + L_) & (L_ - 1);   // nonneg mod, L=128
    const int idxv = s_extr[src];
    if (idxv != 0) atomicMin(&s_first, l);
    __syncthreads();

    const int flag = (l >= s_first) ? 1 : 0;      // cumsum(idx!=0) > 0, inclusive
    const int am   = amax[b * L_ + l];
    const int rA   = (att == 1 && am < V_) ? am : -1;
    const int rB   = flag ? idxv : -1;
    rowA[b * L_ + l] = rA;
    rowB[b * L_ + l] = rB;

    // Every realized row is exactly one W row (or zero): nn = that row's index.
    // Zero row -> all-zero sims -> jnp.argmax ties to 0.
    int nn = (rA >= 0) ? rA : ((rB >= 0) ? rB : 0);
    nn_out[b * L_ + l] = (float)nn;
}

// ---------------------------------------------------------------------------
// Kernel 3: gather W rows into embeds output. One block per (b,l),
// 192 threads x float4 = 768 floats. Bit-exact row copy (0 + x == x).
// ---------------------------------------------------------------------------
__global__ __launch_bounds__(192) void k_gather(
    const float* __restrict__ W,
    const int* __restrict__ rowA, const int* __restrict__ rowB,
    float* __restrict__ out)
{
    const int row = blockIdx.x;
    const int t   = threadIdx.x;   // 0..191
    const int rA = rowA[row];
    const int rB = rowB[row];
    float4 v = make_float4(0.f, 0.f, 0.f, 0.f);
    if (rA >= 0) {
        float4 a = ((const float4*)(W + (size_t)rA * D_))[t];
        v.x += a.x; v.y += a.y; v.z += a.z; v.w += a.w;
    }
    if (rB >= 0) {
        float4 a = ((const float4*)(W + (size_t)rB * D_))[t];
        v.x += a.x; v.y += a.y; v.z += a.z; v.w += a.w;
    }
    ((float4*)(out + (size_t)row * D_))[t] = v;
}

extern "C" void kernel_launch(void* const* d_in, const int* in_sizes, int n_in,
                              void* d_out, int out_size, void* d_ws, size_t ws_size,
                              hipStream_t stream)
{
    const float* logits = (const float*)d_in[0];
    const float* gumbel = (const float*)d_in[1];
    const float* W      = (const float*)d_in[2];
    const int*   rwrt   = (const int*)d_in[3];
    const int*   psg    = (const int*)d_in[4];

    float* out    = (float*)d_out;                       // embeds: 8*128*768
    float* nn_out = out + (size_t)B_ * L_ * D_;          // nn_idx as float: 1024

    int* amax = (int*)d_ws;            // 1024 ints
    int* rowA = amax + B_ * L_;        // 1024 ints
    int* rowB = rowA + B_ * L_;        // 1024 ints

    k_argmax<<<B_ * L_, 256, 0, stream>>>(logits, gumbel, amax);
    k_rowsel<<<B_, L_, 0, stream>>>(rwrt, psg, amax, rowA, rowB, nn_out);
    k_gather<<<B_ * L_, 192, 0, stream>>>(W, rowA, rowB, out);
}

// Round 2
// 324.104 us; speedup vs baseline: 1.0054x; 1.0054x over previous
//
#include <hip/hip_runtime.h>
#include <math.h>
#include <limits.h>

#define B_  8
#define L_  128
#define VF_ 32128
#define V_  32100
#define D_  768

typedef unsigned long long u64;

// Monotone map: f1 > f2  <=>  fmap(f1) > fmap(f2)  (no NaNs in inputs)
__device__ __forceinline__ unsigned int fmap(float f) {
    unsigned int u = __float_as_uint(f);
    return (u & 0x80000000u) ? ~u : (u | 0x80000000u);
}

// ---------------------------------------------------------------------------
// Kernel 1: per-(b,l) argmax over VF of logits+gumbel.
// One 512-thread block per row. 4 independent candidate slots -> 8 outstanding
// 16B loads per pass. Result merged via packed u64 key (value<<32 | VF-idx):
// u64 max == float max with first-index tie-break. Per-wave atomicMax to ws.
// ---------------------------------------------------------------------------
__global__ __launch_bounds__(512) void k_argmax(
    const float* __restrict__ logits, const float* __restrict__ gumbel,
    u64* __restrict__ keys)
{
    const int row = blockIdx.x;                       // 0..1023
    const int tid = threadIdx.x;                      // 0..511
    const float4* lp = (const float4*)(logits + (size_t)row * VF_);
    const float4* gp = (const float4*)(gumbel + (size_t)row * VF_);
    const int NV4 = VF_ / 4;                          // 8032

    float bv0 = -INFINITY, bv1 = -INFINITY, bv2 = -INFINITY, bv3 = -INFINITY;
    int   bi0 = 0, bi1 = 0, bi2 = 0, bi3 = 0;

#define UPD(A, G, I, BV, BI)                                              \
    { float v;                                                            \
      v = (A).x + (G).x; if (v > (BV)) { (BV) = v; (BI) = 4*(I) + 0; }    \
      v = (A).y + (G).y; if (v > (BV)) { (BV) = v; (BI) = 4*(I) + 1; }    \
      v = (A).z + (G).z; if (v > (BV)) { (BV) = v; (BI) = 4*(I) + 2; }    \
      v = (A).w + (G).w; if (v > (BV)) { (BV) = v; (BI) = 4*(I) + 3; } }

#pragma unroll
    for (int p = 0; p < 4; ++p) {
        const int i0 = p * 2048 + tid;
        const int i1 = i0 + 512;
        const int i2 = i0 + 1024;
        const int i3 = i0 + 1536;
        const bool ok3 = (i3 < NV4);      // folds to true for p<3
        float4 A0 = lp[i0], G0 = gp[i0];
        float4 A1 = lp[i1], G1 = gp[i1];
        float4 A2 = lp[i2], G2 = gp[i2];
        float4 A3, G3;
        if (ok3) { A3 = lp[i3]; G3 = gp[i3]; }
        UPD(A0, G0, i0, bv0, bi0)
        UPD(A1, G1, i1, bv1, bi1)
        UPD(A2, G2, i2, bv2, bi2)
        if (ok3) UPD(A3, G3, i3, bv3, bi3)
    }
#undef UPD

    // pack: bigger value wins; equal value -> smaller idx wins (VF-idx larger)
    u64 k0 = ((u64)fmap(bv0) << 32) | (u64)(VF_ - bi0);
    u64 k1 = ((u64)fmap(bv1) << 32) | (u64)(VF_ - bi1);
    u64 k2 = ((u64)fmap(bv2) << 32) | (u64)(VF_ - bi2);
    u64 k3 = ((u64)fmap(bv3) << 32) | (u64)(VF_ - bi3);
    u64 k = k0; if (k1 > k) k = k1; if (k2 > k) k = k2; if (k3 > k) k = k3;

    for (int off = 32; off > 0; off >>= 1) {
        u64 o = __shfl_down(k, off, 64);
        if (o > k) k = o;
    }
    if ((tid & 63) == 0) atomicMax(keys + row, k);
}

// ---------------------------------------------------------------------------
// Kernel 2: per-batch control logic. One block per b, one thread per l.
// ---------------------------------------------------------------------------
__global__ __launch_bounds__(128) void k_rowsel(
    const int* __restrict__ rwrt, const int* __restrict__ psg,
    const u64* __restrict__ keys,
    int* __restrict__ rowA, int* __restrict__ rowB,
    float* __restrict__ nn_out)
{
    const int b = blockIdx.x;
    const int l = threadIdx.x;

    __shared__ int s_att[L_];
    __shared__ int s_extr[L_];
    __shared__ int s_len;
    __shared__ int s_first;

    const int att = rwrt[b * L_ + l];
    s_att[l] = att;
    if (l == 0) s_first = INT_MAX;
    __syncthreads();

    if (l == 0) {
        int len = 0;
        for (int i = 0; i < L_; ++i) len += (s_att[i] == 1);
        s_len = len;
    }
    const int keep = 1 - s_att[L_ - 1 - l];
    s_extr[l] = keep * psg[b * L_ + l];
    __syncthreads();

    const int len  = s_len;
    const int src  = (l - len + L_) & (L_ - 1);
    const int idxv = s_extr[src];
    if (idxv != 0) atomicMin(&s_first, l);
    __syncthreads();

    const int flag = (l >= s_first) ? 1 : 0;
    const int am   = VF_ - (int)(keys[b * L_ + l] & 0xFFFFFFFFull);
    const int rA   = (att == 1 && am < V_) ? am : -1;
    const int rB   = flag ? idxv : -1;
    rowA[b * L_ + l] = rA;
    rowB[b * L_ + l] = rB;

    int nn = (rA >= 0) ? rA : ((rB >= 0) ? rB : 0);
    nn_out[b * L_ + l] = (float)nn;
}

// ---------------------------------------------------------------------------
// Kernel 3: gather W rows into embeds output.
// ---------------------------------------------------------------------------
__global__ __launch_bounds__(192) void k_gather(
    const float* __restrict__ W,
    const int* __restrict__ rowA, const int* __restrict__ rowB,
    float* __restrict__ out)
{
    const int row = blockIdx.x;
    const int t   = threadIdx.x;   // 0..191
    const int rA = rowA[row];
    const int rB = rowB[row];
    float4 v = make_float4(0.f, 0.f, 0.f, 0.f);
    if (rA >= 0) {
        float4 a = ((const float4*)(W + (size_t)rA * D_))[t];
        v.x += a.x; v.y += a.y; v.z += a.z; v.w += a.w;
    }
    if (rB >= 0) {
        float4 a = ((const float4*)(W + (size_t)rB * D_))[t];
        v.x += a.x; v.y += a.y; v.z += a.z; v.w += a.w;
    }
    ((float4*)(out + (size_t)row * D_))[t] = v;
}

extern "C" void kernel_launch(void* const* d_in, const int* in_sizes, int n_in,
                              void* d_out, int out_size, void* d_ws, size_t ws_size,
                              hipStream_t stream)
{
    const float* logits = (const float*)d_in[0];
    const float* gumbel = (const float*)d_in[1];
    const float* W      = (const float*)d_in[2];
    const int*   rwrt   = (const int*)d_in[3];
    const int*   psg    = (const int*)d_in[4];

    float* out    = (float*)d_out;                       // embeds: 8*128*768
    float* nn_out = out + (size_t)B_ * L_ * D_;          // nn_idx as float: 1024

    u64* keys = (u64*)d_ws;                  // 1024 u64 keys
    int* rowA = (int*)(keys + B_ * L_);      // 1024 ints
    int* rowB = rowA + B_ * L_;              // 1024 ints

    hipMemsetAsync(keys, 0, B_ * L_ * sizeof(u64), stream);
    k_argmax<<<B_ * L_, 512, 0, stream>>>(logits, gumbel, keys);
    k_rowsel<<<B_, L_, 0, stream>>>(rwrt, psg, keys, rowA, rowB, nn_out);
    k_gather<<<B_ * L_, 192, 0, stream>>>(W, rowA, rowB, out);
}

// Round 3
// 321.631 us; speedup vs baseline: 1.0132x; 1.0077x over previous
//
#include <hip/hip_runtime.h>
#include <math.h>
#include <limits.h>

#define B_  8
#define L_  128
#define VF_ 32128
#define V_  32100
#define D_  768

#define SEGS_   8          // segments per row
#define SEGF4_  1024       // float4s per segment (1024*4 = 4096 elements)
#define NV4_    (VF_ / 4)  // 8032 float4s per row

typedef unsigned long long u64;

// Monotone map: f1 > f2  <=>  fmap(f1) > fmap(f2)  (inputs have no NaNs)
__device__ __forceinline__ unsigned int fmap(float f) {
    unsigned int u = __float_as_uint(f);
    return (u & 0x80000000u) ? ~u : (u | 0x80000000u);
}

// ---------------------------------------------------------------------------
// Kernel 1: segment-argmax. Grid = rows*SEGS_ blocks of 256 threads; each
// block scans 4096 elements of one row (4 paired float4 loads per thread,
// all 8 loads issued before any compare). Per-wave u64 atomicMax merges
// (value<<32 | VF-idx) -> float max with first-index tie-break.
// Small blocks + <=64 VGPR -> 32 resident waves/CU for max MLP.
// ---------------------------------------------------------------------------
__global__ __launch_bounds__(256, 8) void k_argmax(
    const float* __restrict__ logits, const float* __restrict__ gumbel,
    u64* __restrict__ keys)
{
    const int row = blockIdx.x >> 3;            // 0..1023
    const int seg = blockIdx.x & 7;             // 0..7
    const int tid = threadIdx.x;                // 0..255
    const size_t rowoff = (size_t)row * VF_;
    const float4* lp = (const float4*)(logits + rowoff);
    const float4* gp = (const float4*)(gumbel + rowoff);
    const int base = seg * SEGF4_ + tid;

    float bv = -INFINITY;
    int   bi = 0;

    const int i0 = base;
    const int i1 = base + 256;
    const int i2 = base + 512;
    const int i3 = base + 768;
    const bool k0 = (i0 < NV4_);
    const bool k1 = (i1 < NV4_);
    const bool k2 = (i2 < NV4_);
    const bool k3 = (i3 < NV4_);

    float4 A0, A1, A2, A3, G0, G1, G2, G3;
    if (k0) { A0 = lp[i0]; G0 = gp[i0]; }
    if (k1) { A1 = lp[i1]; G1 = gp[i1]; }
    if (k2) { A2 = lp[i2]; G2 = gp[i2]; }
    if (k3) { A3 = lp[i3]; G3 = gp[i3]; }

#define UPD(A, G, I)                                                  \
    { float v;                                                        \
      v = (A).x + (G).x; if (v > bv) { bv = v; bi = 4*(I) + 0; }      \
      v = (A).y + (G).y; if (v > bv) { bv = v; bi = 4*(I) + 1; }      \
      v = (A).z + (G).z; if (v > bv) { bv = v; bi = 4*(I) + 2; }      \
      v = (A).w + (G).w; if (v > bv) { bv = v; bi = 4*(I) + 3; } }
    if (k0) UPD(A0, G0, i0)
    if (k1) UPD(A1, G1, i1)
    if (k2) UPD(A2, G2, i2)
    if (k3) UPD(A3, G3, i3)
#undef UPD

    // bigger value wins; equal value -> smaller idx (larger VF-idx) wins
    u64 k = ((u64)fmap(bv) << 32) | (u64)(VF_ - bi);
    for (int off = 32; off > 0; off >>= 1) {
        u64 o = __shfl_down(k, off, 64);
        if (o > k) k = o;
    }
    if ((tid & 63) == 0) atomicMax(keys + row, k);
}

// ---------------------------------------------------------------------------
// Kernel 2: per-batch control logic. One block per b, one thread per l.
// ---------------------------------------------------------------------------
__global__ __launch_bounds__(128) void k_rowsel(
    const int* __restrict__ rwrt, const int* __restrict__ psg,
    const u64* __restrict__ keys,
    int* __restrict__ rowA, int* __restrict__ rowB,
    float* __restrict__ nn_out)
{
    const int b = blockIdx.x;
    const int l = threadIdx.x;

    __shared__ int s_att[L_];
    __shared__ int s_extr[L_];
    __shared__ int s_len;
    __shared__ int s_first;

    const int att = rwrt[b * L_ + l];
    s_att[l] = att;
    if (l == 0) s_first = INT_MAX;
    __syncthreads();

    if (l == 0) {
        int len = 0;
        for (int i = 0; i < L_; ++i) len += (s_att[i] == 1);
        s_len = len;
    }
    const int keep = 1 - s_att[L_ - 1 - l];
    s_extr[l] = keep * psg[b * L_ + l];
    __syncthreads();

    const int len  = s_len;
    const int src  = (l - len + L_) & (L_ - 1);
    const int idxv = s_extr[src];
    if (idxv != 0) atomicMin(&s_first, l);
    __syncthreads();

    const int flag = (l >= s_first) ? 1 : 0;
    const int am   = VF_ - (int)(keys[b * L_ + l] & 0xFFFFFFFFull);
    const int rA   = (att == 1 && am < V_) ? am : -1;
    const int rB   = flag ? idxv : -1;
    rowA[b * L_ + l] = rA;
    rowB[b * L_ + l] = rB;

    int nn = (rA >= 0) ? rA : ((rB >= 0) ? rB : 0);
    nn_out[b * L_ + l] = (float)nn;
}

// ---------------------------------------------------------------------------
// Kernel 3: gather W rows into embeds output (exact row copy / sum of two).
// ---------------------------------------------------------------------------
__global__ __launch_bounds__(192) void k_gather(
    const float* __restrict__ W,
    const int* __restrict__ rowA, const int* __restrict__ rowB,
    float* __restrict__ out)
{
    const int row = blockIdx.x;
    const int t   = threadIdx.x;   // 0..191
    const int rA = rowA[row];
    const int rB = rowB[row];
    float4 v = make_float4(0.f, 0.f, 0.f, 0.f);
    if (rA >= 0) {
        float4 a = ((const float4*)(W + (size_t)rA * D_))[t];
        v.x += a.x; v.y += a.y; v.z += a.z; v.w += a.w;
    }
    if (rB >= 0) {
        float4 a = ((const float4*)(W + (size_t)rB * D_))[t];
        v.x += a.x; v.y += a.y; v.z += a.z; v.w += a.w;
    }
    ((float4*)(out + (size_t)row * D_))[t] = v;
}

extern "C" void kernel_launch(void* const* d_in, const int* in_sizes, int n_in,
                              void* d_out, int out_size, void* d_ws, size_t ws_size,
                              hipStream_t stream)
{
    const float* logits = (const float*)d_in[0];
    const float* gumbel = (const float*)d_in[1];
    const float* W      = (const float*)d_in[2];
    const int*   rwrt   = (const int*)d_in[3];
    const int*   psg    = (const int*)d_in[4];

    float* out    = (float*)d_out;                       // embeds: 8*128*768
    float* nn_out = out + (size_t)B_ * L_ * D_;          // nn_idx as float: 1024

    u64* keys = (u64*)d_ws;                  // 1024 u64 keys
    int* rowA = (int*)(keys + B_ * L_);      // 1024 ints
    int* rowB = rowA + B_ * L_;              // 1024 ints

    hipMemsetAsync(keys, 0, B_ * L_ * sizeof(u64), stream);
    k_argmax<<<B_ * L_ * SEGS_, 256, 0, stream>>>(logits, gumbel, keys);
    k_rowsel<<<B_, L_, 0, stream>>>(rwrt, psg, keys, rowA, rowB, nn_out);
    k_gather<<<B_ * L_, 192, 0, stream>>>(W, rowA, rowB, out);
}

// Round 4
// 315.426 us; speedup vs baseline: 1.0331x; 1.0197x over previous
//
#include <hip/hip_runtime.h>
#include <math.h>
#include <limits.h>

#define B_  8
#define L_  128
#define VF_ 32128
#define V_  32100
#define D_  768

#define SEGS_ 8
#define NV4_  (VF_ / 4)   // 8032 float4s per row

typedef unsigned long long u64;

// Monotone map: f1 > f2  <=>  fmap(f1) > fmap(f2)  (inputs have no NaNs)
__device__ __forceinline__ unsigned int fmap(float f) {
    unsigned int u = __float_as_uint(f);
    return (u & 0x80000000u) ? ~u : (u | 0x80000000u);
}

// ---------------------------------------------------------------------------
// Kernel 1: segment argmax of logits+gumbel. Grid = 1024 rows x 8 segs,
// 256 threads. Each thread: 4 UNCONDITIONAL paired float4 loads (indices
// clamped to row end -- clamped lanes reproduce element 8031's (value,idx),
// harmless under max with first-index tie-break). All 8 loads issued before
// any compare; 128-VGPR cap so the compiler keeps them in flight.
// Per-block result -> plain store keys[row*8+seg] (no atomics, no memset).
// ---------------------------------------------------------------------------
__global__ __launch_bounds__(256, 4) void k_argmax(
    const float* __restrict__ logits, const float* __restrict__ gumbel,
    u64* __restrict__ keys)
{
    const int row = blockIdx.x >> 3;            // 0..1023
    const int seg = blockIdx.x & 7;             // 0..7
    const int tid = threadIdx.x;                // 0..255
    const size_t rowoff = (size_t)row * VF_;
    const float4* lp = (const float4*)(logits + rowoff);
    const float4* gp = (const float4*)(gumbel + rowoff);

    const int base = (seg << 10) + tid;         // segment = 1024 float4s
    int i0 = base;
    int i1 = base + 256;
    int i2 = base + 512;
    int i3 = base + 768;
    i0 = i0 < NV4_ - 1 ? i0 : NV4_ - 1;
    i1 = i1 < NV4_ - 1 ? i1 : NV4_ - 1;
    i2 = i2 < NV4_ - 1 ? i2 : NV4_ - 1;
    i3 = i3 < NV4_ - 1 ? i3 : NV4_ - 1;

    float4 A0 = lp[i0]; float4 G0 = gp[i0];
    float4 A1 = lp[i1]; float4 G1 = gp[i1];
    float4 A2 = lp[i2]; float4 G2 = gp[i2];
    float4 A3 = lp[i3]; float4 G3 = gp[i3];

    float bv = -INFINITY;
    int   bi = 0;
#define UPD(A, G, I)                                                  \
    { float v;                                                        \
      v = (A).x + (G).x; if (v > bv) { bv = v; bi = 4*(I) + 0; }      \
      v = (A).y + (G).y; if (v > bv) { bv = v; bi = 4*(I) + 1; }      \
      v = (A).z + (G).z; if (v > bv) { bv = v; bi = 4*(I) + 2; }      \
      v = (A).w + (G).w; if (v > bv) { bv = v; bi = 4*(I) + 3; } }
    UPD(A0, G0, i0)
    UPD(A1, G1, i1)
    UPD(A2, G2, i2)
    UPD(A3, G3, i3)
#undef UPD

    // bigger value wins; equal value -> smaller idx (larger VF-idx) wins
    u64 k = ((u64)fmap(bv) << 32) | (u64)(VF_ - bi);
    for (int off = 32; off > 0; off >>= 1) {
        u64 o = __shfl_down(k, off, 64);
        if (o > k) k = o;
    }
    __shared__ u64 s_k[4];
    if ((tid & 63) == 0) s_k[tid >> 6] = k;
    __syncthreads();
    if (tid == 0) {
        u64 kk = s_k[0];
        if (s_k[1] > kk) kk = s_k[1];
        if (s_k[2] > kk) kk = s_k[2];
        if (s_k[3] > kk) kk = s_k[3];
        keys[blockIdx.x] = kk;
    }
}

// ---------------------------------------------------------------------------
// Kernel 2 (fused): per-(b,l) block. Merges the row's 8 segment keys,
// redundantly recomputes the per-b control logic (cheap: 256 int loads),
// then gathers the W row(s) into the output. 192 threads (768 floats / f4).
// ---------------------------------------------------------------------------
__global__ __launch_bounds__(192) void k_emb(
    const float* __restrict__ W,
    const int* __restrict__ rwrt, const int* __restrict__ psg,
    const u64* __restrict__ keys,
    float* __restrict__ out, float* __restrict__ nn_out)
{
    const int row = blockIdx.x;          // b*128 + l
    const int b = row >> 7;
    const int l = row & 127;
    const int t = threadIdx.x;           // 0..191

    __shared__ int s_att[L_];
    __shared__ int s_extr[L_];
    __shared__ u64 s_keys[SEGS_];
    __shared__ int s_len, s_first, s_rA, s_rB;

    if (t == 0) s_first = INT_MAX;
    if (t < L_) s_att[t] = rwrt[b * L_ + t];
    if (t >= 128 && t < 128 + SEGS_) s_keys[t - 128] = keys[row * SEGS_ + (t - 128)];
    __syncthreads();

    if (t == 0) {
        int len = 0;
        for (int i = 0; i < L_; ++i) len += (s_att[i] == 1);
        s_len = len;
    }
    if (t < L_) s_extr[t] = (1 - s_att[L_ - 1 - t]) * psg[b * L_ + t];
    __syncthreads();

    if (t < L_) {
        int src = (t - s_len + L_) & (L_ - 1);
        if (s_extr[src] != 0) atomicMin(&s_first, t);
    }
    __syncthreads();

    if (t == 0) {
        u64 kk = s_keys[0];
        #pragma unroll
        for (int i = 1; i < SEGS_; ++i) if (s_keys[i] > kk) kk = s_keys[i];
        const int am   = VF_ - (int)(kk & 0xFFFFFFFFull);
        const int srcl = (l - s_len + L_) & (L_ - 1);
        const int idxv = s_extr[srcl];
        const int flag = (l >= s_first) ? 1 : 0;
        const int rA = (s_att[l] == 1 && am < V_) ? am : -1;
        const int rB = flag ? idxv : -1;
        s_rA = rA; s_rB = rB;
        // Every realized row is exactly one W row (or zero): nn = its index.
        // Zero row -> all-zero sims -> jnp.argmax ties to 0.
        const int nn = (rA >= 0) ? rA : ((rB >= 0) ? rB : 0);
        nn_out[row] = (float)nn;
    }
    __syncthreads();

    const int rA = s_rA;
    const int rB = s_rB;
    float4 v = make_float4(0.f, 0.f, 0.f, 0.f);
    if (rA >= 0) {
        float4 a = ((const float4*)(W + (size_t)rA * D_))[t];
        v.x += a.x; v.y += a.y; v.z += a.z; v.w += a.w;
    }
    if (rB >= 0) {
        float4 a = ((const float4*)(W + (size_t)rB * D_))[t];
        v.x += a.x; v.y += a.y; v.z += a.z; v.w += a.w;
    }
    ((float4*)(out + (size_t)row * D_))[t] = v;
}

extern "C" void kernel_launch(void* const* d_in, const int* in_sizes, int n_in,
                              void* d_out, int out_size, void* d_ws, size_t ws_size,
                              hipStream_t stream)
{
    const float* logits = (const float*)d_in[0];
    const float* gumbel = (const float*)d_in[1];
    const float* W      = (const float*)d_in[2];
    const int*   rwrt   = (const int*)d_in[3];
    const int*   psg    = (const int*)d_in[4];

    float* out    = (float*)d_out;                       // embeds: 8*128*768
    float* nn_out = out + (size_t)B_ * L_ * D_;          // nn_idx as float: 1024

    u64* keys = (u64*)d_ws;                  // 8192 u64 segment keys (64 KB)

    k_argmax<<<B_ * L_ * SEGS_, 256, 0, stream>>>(logits, gumbel, keys);
    k_emb<<<B_ * L_, 192, 0, stream>>>(W, rwrt, psg, keys, out, nn_out);
}